// Round 1
// baseline (359.721 us; speedup 1.0000x reference)
//
#include <hip/hip_runtime.h>
#include <math.h>

#define NB 8192
#define NC 128
#define NJS 8          // j-slices
#define JPT 8          // j-tiles of 128 per slice
#define NTAIL 32       // phase-3 blocks (NB/256)

typedef float v4f __attribute__((ext_vector_type(4)));
typedef int   v8i __attribute__((ext_vector_type(8)));   // 32 fp8 (8 VGPRs)

// Software grid barrier: all 1024 blocks are co-resident by construction
// (grid = 256 CU x 4 blocks/CU, __launch_bounds__(256,4), LDS = 40960 B
// exactly -> 4 blocks/CU). Monotonic counter, per-phase target, agent-scope
// atomics + device fences for cross-XCD visibility (per-XCD L2s are not
// coherent without them).
__device__ __forceinline__ void grid_sync(unsigned* bar, unsigned target) {
    __syncthreads();
    if (threadIdx.x == 0) {
        __threadfence();   // release: drain + make this block's stores visible device-wide
        __hip_atomic_fetch_add(bar, 1u, __ATOMIC_ACQ_REL, __HIP_MEMORY_SCOPE_AGENT);
        while (__hip_atomic_load(bar, __ATOMIC_ACQUIRE, __HIP_MEMORY_SCOPE_AGENT) < target)
            __builtin_amdgcn_s_sleep(2);
        __threadfence();   // acquire: invalidate stale L1/L2 before reading peers' data
    }
    __syncthreads();
}

// ---------------------------------------------------------------- fused:
// phase 1 (prep): fp8 cast + sum-of-squares + CE term, 8 rows/block.
// phase 2 (trip): FP8 MX MFMA GEMM, identical to the verified k_trip
//   (64x128 block tile, B double-buffered + XOR-swizzled, one K=128 MFMA
//   per 16x16 tile, fused hardest-pos/neg epilogue).
// phase 3 (tail): 32 blocks combine 16 slices, hinge + CE sums, last
//   block runs the Lambert-W scalar.
// Fusing removes two dependent kernel dispatches (launch overhead was the
// dominant non-poison cost); grid barriers provide the ordering the
// separate launches used to.
__global__ __launch_bounds__(256, 4) void k_fused(const float* __restrict__ x,
                                                  const int* __restrict__ tgt,
                                                  unsigned* __restrict__ xqu,   // NB*32 uints (4 fp8 each)
                                                  float* __restrict__ sq,
                                                  float* __restrict__ ce,
                                                  float* __restrict__ sums,
                                                  unsigned* __restrict__ cnt,
                                                  unsigned* __restrict__ bar,
                                                  float* __restrict__ pmax,     // [16][NB]
                                                  float* __restrict__ pmin,     // [16][NB]
                                                  float* __restrict__ out) {
    // Phase-3 smem overlaid on phase-2 smem: total stays 40960 B so
    // 4 blocks/CU (= 160 KiB/CU exactly) is preserved -> barrier is safe.
    __shared__ union {
        struct { unsigned char Bs[2][128 * 128]; float sqs[1024]; int tjs[1024]; } p2;
        struct { float sh[4]; float sc[4]; unsigned lastFlag; } p3;
    } sm;

    const int tid = threadIdx.x;

    // ---------------- phase 1: prep ----------------
    {
        int row = blockIdx.x * 8 + (tid >> 5);
        int l = tid & 31;
        float4 v = ((const float4*)(x + row * NC))[l];
        unsigned p = __builtin_amdgcn_cvt_pk_fp8_f32(v.x, v.y, 0, false);
        p = __builtin_amdgcn_cvt_pk_fp8_f32(v.z, v.w, p, true);
        xqu[row * 32 + l] = p;

        float ss = fmaf(v.x, v.x, fmaf(v.y, v.y, fmaf(v.z, v.z, v.w * v.w)));
        float mx = fmaxf(fmaxf(v.x, v.y), fmaxf(v.z, v.w));
#pragma unroll
        for (int off = 16; off; off >>= 1) {        // offsets <32: stay within half-wave
            ss += __shfl_xor(ss, off);
            mx = fmaxf(mx, __shfl_xor(mx, off));
        }
        float es = expf(v.x - mx) + expf(v.y - mx) + expf(v.z - mx) + expf(v.w - mx);
#pragma unroll
        for (int off = 16; off; off >>= 1) es += __shfl_xor(es, off);
        if (l == 0) {
            sq[row] = ss;
            ce[row] = mx + logf(es) - x[row * NC + tgt[row]];
        }
        // sums/cnt/bar are zeroed by the pre-kernel memset (poison-proof).
    }

    grid_sync(bar, 1024u);   // all xq/sq/ce visible device-wide

    // ---------------- phase 2: triplet GEMM ----------------
    const unsigned char* xq = (const unsigned char*)xqu;
    {
        const int lane = tid & 63;
        const int w = tid >> 6;           // wave 0..3
        const int rh = w >> 1;            // row half (32 rows)
        const int ch = w & 1;             // col half (64 cols)
        const int by = (int)blockIdx.x >> 7;      // j-slice 0..7
        const int bx = (int)blockIdx.x & 127;     // row block 0..127
        const int i0 = bx * 64;
        const int jbase = by * 1024;
        const int m = lane & 15;
        const int quad = lane >> 4;

        // ---- stage j-slice metadata via async-LDS ----
        __builtin_amdgcn_global_load_lds(
            (const __attribute__((address_space(1))) unsigned*)((const unsigned*)(sq + jbase) + (w * 64 + lane) * 4),
            (__attribute__((address_space(3))) unsigned*)(sm.p2.sqs + w * 256),
            16, 0, 0);
        __builtin_amdgcn_global_load_lds(
            (const __attribute__((address_space(1))) unsigned*)((const unsigned*)(tgt + jbase) + (w * 64 + lane) * 4),
            (__attribute__((address_space(3))) unsigned*)(sm.p2.tjs + w * 256),
            16, 0, 0);

        // ---- stage B tile 0 into buffer 0 (async) ----
#pragma unroll
        for (int c = 0; c < 4; ++c) {
            int L = w * 256 + c * 64 + lane;          // 16-B chunk index 0..1023
            int col = L >> 3, cc = L & 7;
            const unsigned char* src = xq + (size_t)(jbase + col) * 128 + ((cc ^ (col & 7)) << 4);
            __builtin_amdgcn_global_load_lds(
                (const __attribute__((address_space(1))) unsigned*)src,
                (__attribute__((address_space(3))) unsigned*)(&sm.p2.Bs[0][0] + (w * 256 + c * 64) * 16),
                16, 0, 0);
        }

        // ---- A fragments straight into registers ----
        v8i a[2];
#pragma unroll
        for (int tm = 0; tm < 2; ++tm) {
            int row = i0 + rh * 32 + tm * 16 + m;
            a[tm] = *(const v8i*)(xq + (size_t)row * 128 + quad * 32);
        }

        // ---- anchor targets for this lane's output rows ----
        int ti[2][4];
#pragma unroll
        for (int tm = 0; tm < 2; ++tm)
#pragma unroll
            for (int r = 0; r < 4; ++r)
                ti[tm][r] = tgt[i0 + rh * 32 + tm * 16 + quad * 4 + r];

        float mp[2][4], mn[2][4];
#pragma unroll
        for (int tm = 0; tm < 2; ++tm)
#pragma unroll
            for (int r = 0; r < 4; ++r) { mp[tm][r] = -3.0e38f; mn[tm][r] = 3.0e38f; }

#pragma unroll 2
        for (int jt = 0; jt < JPT; ++jt) {
            // drains the prefetch issued one full iteration ago (~free) and
            // ensures all waves are done reading the buffer we're about to fill
            __syncthreads();

            // ---- early-issue prefetch of NEXT B tile into the other buffer ----
            if (jt + 1 < JPT) {
                int jn = jbase + (jt + 1) * 128;
                unsigned char* Bnxt = &sm.p2.Bs[(jt + 1) & 1][0];
#pragma unroll
                for (int c = 0; c < 4; ++c) {
                    int L = w * 256 + c * 64 + lane;
                    int col = L >> 3, cc = L & 7;
                    const unsigned char* src = xq + (size_t)(jn + col) * 128 + ((cc ^ (col & 7)) << 4);
                    __builtin_amdgcn_global_load_lds(
                        (const __attribute__((address_space(1))) unsigned*)src,
                        (__attribute__((address_space(3))) unsigned*)(Bnxt + (w * 256 + c * 64) * 16),
                        16, 0, 0);
                }
            }

            const unsigned char* Bcur = &sm.p2.Bs[jt & 1][0];

            // ---- column metadata from LDS ----
            float sqj[4]; int tj[4];
#pragma unroll
            for (int tn = 0; tn < 4; ++tn) {
                int cloc = jt * 128 + ch * 64 + tn * 16 + m;
                sqj[tn] = sm.p2.sqs[cloc];
                tj[tn] = sm.p2.tjs[cloc];
            }

            // ---- b fragments: 32 B/lane = two b128 reads (XOR-swizzled) ----
            v8i b[4];
#pragma unroll
            for (int tn = 0; tn < 4; ++tn) {
                int col = ch * 64 + tn * 16 + m;
                int base = col * 128;
                int c0 = (((quad * 2) ^ (col & 7)) << 4);
                int c1 = (((quad * 2 + 1) ^ (col & 7)) << 4);
                *(int4*)&b[tn] = *(const int4*)(Bcur + base + c0);
                *((int4*)&b[tn] + 1) = *(const int4*)(Bcur + base + c1);
            }

            // ---- one MX MFMA per (tm,tn) covers all K=128; scales = 1.0 ----
            v4f acc[2][4];
            v4f z = {0.0f, 0.0f, 0.0f, 0.0f};
#pragma unroll
            for (int tm = 0; tm < 2; ++tm)
#pragma unroll
                for (int tn = 0; tn < 4; ++tn)
                    acc[tm][tn] = __builtin_amdgcn_mfma_scale_f32_16x16x128_f8f6f4(
                        a[tm], b[tn], z, 0, 0, 0, 0x7f7f7f7f, 0, 0x7f7f7f7f);

            // ---- fused epilogue: v = sqj - 2*dot (sqi added in phase 3) ----
#pragma unroll
            for (int tn = 0; tn < 4; ++tn) {
#pragma unroll
                for (int tm = 0; tm < 2; ++tm)
#pragma unroll
                    for (int r = 0; r < 4; ++r) {
                        float v = fmaf(-2.0f, acc[tm][tn][r], sqj[tn]);
                        bool pos = (tj[tn] == ti[tm][r]);
                        mp[tm][r] = fmaxf(mp[tm][r], pos ? v : -3.0e38f);
                        mn[tm][r] = fminf(mn[tm][r], pos ? 3.0e38f : v);
                    }
            }
        }

        // ---- reduce across the 16 lanes (lane&15) sharing each output row ----
#pragma unroll
        for (int off = 1; off < 16; off <<= 1) {
#pragma unroll
            for (int tm = 0; tm < 2; ++tm)
#pragma unroll
                for (int r = 0; r < 4; ++r) {
                    mp[tm][r] = fmaxf(mp[tm][r], __shfl_xor(mp[tm][r], off));
                    mn[tm][r] = fminf(mn[tm][r], __shfl_xor(mn[tm][r], off));
                }
        }
        // ---- plain stores to this wave's private (slice, row-range) ----
        if (m == 0) {
            int slice = by * 2 + ch;
            float* pm = pmax + (size_t)slice * NB + i0 + rh * 32;
            float* pn = pmin + (size_t)slice * NB + i0 + rh * 32;
#pragma unroll
            for (int tm = 0; tm < 2; ++tm)
#pragma unroll
                for (int r = 0; r < 4; ++r) {
                    int rr = tm * 16 + quad * 4 + r;
                    pm[rr] = mp[tm][r];
                    pn[rr] = mn[tm][r];
                }
        }
    }

    grid_sync(bar, 2048u);   // all pmax/pmin visible device-wide

    // ---------------- phase 3: tail (32 blocks) ----------------
    if (blockIdx.x >= NTAIL) return;
    {
        int i = blockIdx.x * 256 + tid;
        float vmax = -3.0e38f, vmin = 3.0e38f;
#pragma unroll
        for (int s = 0; s < 16; ++s) {
            vmax = fmaxf(vmax, pmax[s * NB + i]);
            vmin = fminf(vmin, pmin[s * NB + i]);
        }
        float sqi = sq[i];
        float ap = sqrtf(fmaxf(fmaxf(sqi + vmax, 0.0f), 1e-12f));
        float an = sqrtf(fmaxf(fmaxf(sqi + vmin, 0.0f), 1e-12f));
        float hs = fmaxf(ap - an + 0.3f, 0.0f);
        float cs = ce[i];
#pragma unroll
        for (int off = 32; off; off >>= 1) {
            hs += __shfl_xor(hs, off);
            cs += __shfl_xor(cs, off);
        }
        int wv = tid >> 6;
        if ((tid & 63) == 0) { sm.p3.sh[wv] = hs; sm.p3.sc[wv] = cs; }
        __syncthreads();
        if (tid == 0) {
            float H = sm.p3.sh[0] + sm.p3.sh[1] + sm.p3.sh[2] + sm.p3.sh[3];
            float Cs = sm.p3.sc[0] + sm.p3.sc[1] + sm.p3.sc[2] + sm.p3.sc[3];
            atomicAdd(sums + 0, H);
            atomicAdd(sums + 1, Cs);
            __threadfence();
            unsigned prev = atomicAdd(cnt, 1u);
            sm.p3.lastFlag = (prev == (unsigned)(NTAIL - 1));
        }
        __syncthreads();
        if (!sm.p3.lastFlag || tid != 0) return;

        // last block, thread 0: scalar Lambert-W tail
        double H = (double)atomicAdd(sums + 0, 0.0f);
        double Cs = (double)atomicAdd(sums + 1, 0.0f);
        const double E = 2.71828182845904523536;
        const double TAU = log(128.0);
        const double LAMd = 0.25;
        double l = H / (double)NB;
        double cev = Cs / (double)NB;
        double y = 0.5 * fmax(-2.0 / E, (l - TAU) / LAMd);
        double p = sqrt(fmax(2.0 * (E * y + 1.0), 0.0));
        double wn = -1.0 + p - p * p / 3.0 + (11.0 / 72.0) * p * p * p;
        double wlw = (y < 0.0) ? wn : log1p(fmax(y, 0.0));
#pragma unroll
        for (int it = 0; it < 10; ++it) {
            double ew = exp(wlw);
            double f = wlw * ew - y;
            double wp1 = wlw + 1.0;
            wlw = wlw - f / (ew * wp1 - (wlw + 2.0) * f / (2.0 * wp1));
        }
        double sigma = exp(-wlw);
        double lg = log(sigma);
        double loss = (cev - TAU) * sigma + LAMd * lg * lg;
        out[0] = (float)(loss / (double)NB);
    }
}

// ---------------------------------------------------------------- launcher
extern "C" void kernel_launch(void* const* d_in, const int* in_sizes, int n_in,
                              void* d_out, int out_size, void* d_ws, size_t ws_size,
                              hipStream_t stream) {
    const float* x = (const float*)d_in[0];
    const int* tgt = (const int*)d_in[1];
    float* out = (float*)d_out;

    // ws: xq (NB*128 B = 1 MB) | sq | ce | sums[2] | cnt | bar | pad | pmax | pmin
    unsigned char* xq = (unsigned char*)d_ws;
    float* sq = (float*)(xq + (size_t)NB * 128);
    float* ce = sq + NB;
    float* sums = ce + NB;
    unsigned* cnt = (unsigned*)(sums + 2);
    unsigned* bar = cnt + 1;
    float* pmax = (float*)(cnt + 62);              // keep 256-B alignment
    float* pmin = pmax + (size_t)16 * NB;

    // zero sums/cnt/bar (256 B) — poison-proof, captured in the graph
    hipMemsetAsync(sums, 0, 256, stream);
    k_fused<<<dim3(1024), dim3(256), 0, stream>>>(x, tgt, (unsigned*)xq, sq, ce, sums, cnt,
                                                  bar, pmax, pmin, out);
}

// Round 2
// 289.740 us; speedup vs baseline: 1.2415x; 1.2415x over previous
//
#include <hip/hip_runtime.h>
#include <math.h>

#define NB 8192
#define NC 128
#define NJS 8          // j-slices
#define JPT 8          // j-tiles of 128 per slice
#define NTAIL 32       // phase-3 blocks (NB/256)

typedef float v4f __attribute__((ext_vector_type(4)));
typedef int   v8i __attribute__((ext_vector_type(8)));   // 32 fp8 (8 VGPRs)

// ---------------------------------------------------------------- barrier:
// Two-level grid barrier, contention-decoupled. Round-1 lesson: a single
// counter line polled by 1024 acquire-loads while 1024 fetch_adds target it
// serializes arrivals at ~140 ns each (~140 us/barrier). Here:
//   leaf[16] (128-B lines): 64 adds each, ZERO readers  -> adds pipeline
//   root     (own line):    16 adds,      ZERO readers
//   flag     (own line):    1 release-store per phase; everyone polls THIS
// ctl layout (unsigned words): root = ctl[32] (+128B), flag = ctl[64]
// (+256B), leaf g = ctl[128 + g*32] (+512B + g*128B). All zeroed by the
// pre-kernel memset. All 1024 blocks are co-resident by construction
// (grid = 256 CU x 4 blocks/CU; LDS 40960 B x 4 = 160 KiB/CU exactly).
__device__ __forceinline__ void grid_sync(unsigned* ctl, unsigned phase) {
    __syncthreads();
    if (threadIdx.x == 0) {
        __threadfence();   // release: this block's stores visible device-wide
        unsigned g = (unsigned)blockIdx.x & 15u;
        unsigned prev = __hip_atomic_fetch_add(ctl + 128 + g * 32, 1u,
                                               __ATOMIC_ACQ_REL, __HIP_MEMORY_SCOPE_AGENT);
        if (prev == phase * 64u - 1u) {
            unsigned pr = __hip_atomic_fetch_add(ctl + 32, 1u,
                                                 __ATOMIC_ACQ_REL, __HIP_MEMORY_SCOPE_AGENT);
            if (pr == phase * 16u - 1u)
                __hip_atomic_store(ctl + 64, phase,
                                   __ATOMIC_RELEASE, __HIP_MEMORY_SCOPE_AGENT);
        }
        while (__hip_atomic_load(ctl + 64, __ATOMIC_ACQUIRE, __HIP_MEMORY_SCOPE_AGENT) < phase)
            __builtin_amdgcn_s_sleep(16);
        __threadfence();   // acquire side: refresh caches before reading peers' data
    }
    __syncthreads();
}

// ---------------------------------------------------------------- fused:
// phase 1 (prep): fp8 cast + sum-of-squares + CE term, 8 rows/block.
// phase 2 (trip): FP8 MX MFMA GEMM (64x128 block tile, B double-buffered +
//   XOR-swizzled, one K=128 MFMA per 16x16 tile, fused hardest-pos/neg
//   epilogue).
// phase 3 (tail): 32 blocks combine 16 slices, hinge + CE sums, last
//   block runs the Lambert-W scalar.
__global__ __launch_bounds__(256, 4) void k_fused(const float* __restrict__ x,
                                                  const int* __restrict__ tgt,
                                                  unsigned* __restrict__ xqu,   // NB*32 uints (4 fp8 each)
                                                  float* __restrict__ sq,
                                                  float* __restrict__ ce,
                                                  float* __restrict__ sums,
                                                  unsigned* __restrict__ cnt,
                                                  unsigned* __restrict__ ctl,
                                                  float* __restrict__ pmax,     // [16][NB]
                                                  float* __restrict__ pmin,     // [16][NB]
                                                  float* __restrict__ out) {
    // Phase-3 smem overlaid on phase-2 smem: total stays 40960 B so
    // 4 blocks/CU (= 160 KiB/CU exactly) is preserved -> barrier is safe.
    __shared__ union {
        struct { unsigned char Bs[2][128 * 128]; float sqs[1024]; int tjs[1024]; } p2;
        struct { float sh[4]; float sc[4]; unsigned lastFlag; } p3;
    } sm;

    const int tid = threadIdx.x;

    // ---------------- phase 1: prep ----------------
    {
        int row = blockIdx.x * 8 + (tid >> 5);
        int l = tid & 31;
        float4 v = ((const float4*)(x + row * NC))[l];
        unsigned p = __builtin_amdgcn_cvt_pk_fp8_f32(v.x, v.y, 0, false);
        p = __builtin_amdgcn_cvt_pk_fp8_f32(v.z, v.w, p, true);
        xqu[row * 32 + l] = p;

        float ss = fmaf(v.x, v.x, fmaf(v.y, v.y, fmaf(v.z, v.z, v.w * v.w)));
        float mx = fmaxf(fmaxf(v.x, v.y), fmaxf(v.z, v.w));
#pragma unroll
        for (int off = 16; off; off >>= 1) {        // offsets <32: stay within half-wave
            ss += __shfl_xor(ss, off);
            mx = fmaxf(mx, __shfl_xor(mx, off));
        }
        float es = expf(v.x - mx) + expf(v.y - mx) + expf(v.z - mx) + expf(v.w - mx);
#pragma unroll
        for (int off = 16; off; off >>= 1) es += __shfl_xor(es, off);
        if (l == 0) {
            sq[row] = ss;
            ce[row] = mx + logf(es) - x[row * NC + tgt[row]];
        }
        // sums/cnt/ctl are zeroed by the pre-kernel memset (poison-proof).
    }

    grid_sync(ctl, 1u);   // all xq/sq/ce visible device-wide

    // ---------------- phase 2: triplet GEMM ----------------
    const unsigned char* xq = (const unsigned char*)xqu;
    {
        const int lane = tid & 63;
        const int w = tid >> 6;           // wave 0..3
        const int rh = w >> 1;            // row half (32 rows)
        const int ch = w & 1;             // col half (64 cols)
        const int by = (int)blockIdx.x >> 7;      // j-slice 0..7
        const int bx = (int)blockIdx.x & 127;     // row block 0..127
        const int i0 = bx * 64;
        const int jbase = by * 1024;
        const int m = lane & 15;
        const int quad = lane >> 4;

        // ---- stage j-slice metadata via async-LDS ----
        __builtin_amdgcn_global_load_lds(
            (const __attribute__((address_space(1))) unsigned*)((const unsigned*)(sq + jbase) + (w * 64 + lane) * 4),
            (__attribute__((address_space(3))) unsigned*)(sm.p2.sqs + w * 256),
            16, 0, 0);
        __builtin_amdgcn_global_load_lds(
            (const __attribute__((address_space(1))) unsigned*)((const unsigned*)(tgt + jbase) + (w * 64 + lane) * 4),
            (__attribute__((address_space(3))) unsigned*)(sm.p2.tjs + w * 256),
            16, 0, 0);

        // ---- stage B tile 0 into buffer 0 (async) ----
#pragma unroll
        for (int c = 0; c < 4; ++c) {
            int L = w * 256 + c * 64 + lane;          // 16-B chunk index 0..1023
            int col = L >> 3, cc = L & 7;
            const unsigned char* src = xq + (size_t)(jbase + col) * 128 + ((cc ^ (col & 7)) << 4);
            __builtin_amdgcn_global_load_lds(
                (const __attribute__((address_space(1))) unsigned*)src,
                (__attribute__((address_space(3))) unsigned*)(&sm.p2.Bs[0][0] + (w * 256 + c * 64) * 16),
                16, 0, 0);
        }

        // ---- A fragments straight into registers ----
        v8i a[2];
#pragma unroll
        for (int tm = 0; tm < 2; ++tm) {
            int row = i0 + rh * 32 + tm * 16 + m;
            a[tm] = *(const v8i*)(xq + (size_t)row * 128 + quad * 32);
        }

        // ---- anchor targets for this lane's output rows ----
        int ti[2][4];
#pragma unroll
        for (int tm = 0; tm < 2; ++tm)
#pragma unroll
            for (int r = 0; r < 4; ++r)
                ti[tm][r] = tgt[i0 + rh * 32 + tm * 16 + quad * 4 + r];

        float mp[2][4], mn[2][4];
#pragma unroll
        for (int tm = 0; tm < 2; ++tm)
#pragma unroll
            for (int r = 0; r < 4; ++r) { mp[tm][r] = -3.0e38f; mn[tm][r] = 3.0e38f; }

#pragma unroll 2
        for (int jt = 0; jt < JPT; ++jt) {
            // drains the prefetch issued one full iteration ago (~free) and
            // ensures all waves are done reading the buffer we're about to fill
            __syncthreads();

            // ---- early-issue prefetch of NEXT B tile into the other buffer ----
            if (jt + 1 < JPT) {
                int jn = jbase + (jt + 1) * 128;
                unsigned char* Bnxt = &sm.p2.Bs[(jt + 1) & 1][0];
#pragma unroll
                for (int c = 0; c < 4; ++c) {
                    int L = w * 256 + c * 64 + lane;
                    int col = L >> 3, cc = L & 7;
                    const unsigned char* src = xq + (size_t)(jn + col) * 128 + ((cc ^ (col & 7)) << 4);
                    __builtin_amdgcn_global_load_lds(
                        (const __attribute__((address_space(1))) unsigned*)src,
                        (__attribute__((address_space(3))) unsigned*)(Bnxt + (w * 256 + c * 64) * 16),
                        16, 0, 0);
                }
            }

            const unsigned char* Bcur = &sm.p2.Bs[jt & 1][0];

            // ---- column metadata from LDS ----
            float sqj[4]; int tj[4];
#pragma unroll
            for (int tn = 0; tn < 4; ++tn) {
                int cloc = jt * 128 + ch * 64 + tn * 16 + m;
                sqj[tn] = sm.p2.sqs[cloc];
                tj[tn] = sm.p2.tjs[cloc];
            }

            // ---- b fragments: 32 B/lane = two b128 reads (XOR-swizzled) ----
            v8i b[4];
#pragma unroll
            for (int tn = 0; tn < 4; ++tn) {
                int col = ch * 64 + tn * 16 + m;
                int base = col * 128;
                int c0 = (((quad * 2) ^ (col & 7)) << 4);
                int c1 = (((quad * 2 + 1) ^ (col & 7)) << 4);
                *(int4*)&b[tn] = *(const int4*)(Bcur + base + c0);
                *((int4*)&b[tn] + 1) = *(const int4*)(Bcur + base + c1);
            }

            // ---- one MX MFMA per (tm,tn) covers all K=128; scales = 1.0 ----
            v4f acc[2][4];
            v4f z = {0.0f, 0.0f, 0.0f, 0.0f};
#pragma unroll
            for (int tm = 0; tm < 2; ++tm)
#pragma unroll
                for (int tn = 0; tn < 4; ++tn)
                    acc[tm][tn] = __builtin_amdgcn_mfma_scale_f32_16x16x128_f8f6f4(
                        a[tm], b[tn], z, 0, 0, 0, 0x7f7f7f7f, 0, 0x7f7f7f7f);

            // ---- fused epilogue: v = sqj - 2*dot (sqi added in phase 3) ----
#pragma unroll
            for (int tn = 0; tn < 4; ++tn) {
#pragma unroll
                for (int tm = 0; tm < 2; ++tm)
#pragma unroll
                    for (int r = 0; r < 4; ++r) {
                        float v = fmaf(-2.0f, acc[tm][tn][r], sqj[tn]);
                        bool pos = (tj[tn] == ti[tm][r]);
                        mp[tm][r] = fmaxf(mp[tm][r], pos ? v : -3.0e38f);
                        mn[tm][r] = fminf(mn[tm][r], pos ? 3.0e38f : v);
                    }
            }
        }

        // ---- reduce across the 16 lanes (lane&15) sharing each output row ----
#pragma unroll
        for (int off = 1; off < 16; off <<= 1) {
#pragma unroll
            for (int tm = 0; tm < 2; ++tm)
#pragma unroll
                for (int r = 0; r < 4; ++r) {
                    mp[tm][r] = fmaxf(mp[tm][r], __shfl_xor(mp[tm][r], off));
                    mn[tm][r] = fminf(mn[tm][r], __shfl_xor(mn[tm][r], off));
                }
        }
        // ---- plain stores to this wave's private (slice, row-range) ----
        if (m == 0) {
            int slice = by * 2 + ch;
            float* pm = pmax + (size_t)slice * NB + i0 + rh * 32;
            float* pn = pmin + (size_t)slice * NB + i0 + rh * 32;
#pragma unroll
            for (int tm = 0; tm < 2; ++tm)
#pragma unroll
                for (int r = 0; r < 4; ++r) {
                    int rr = tm * 16 + quad * 4 + r;
                    pm[rr] = mp[tm][r];
                    pn[rr] = mn[tm][r];
                }
        }
    }

    grid_sync(ctl, 2u);   // all pmax/pmin visible device-wide

    // ---------------- phase 3: tail (32 blocks) ----------------
    if (blockIdx.x >= NTAIL) return;
    {
        int i = blockIdx.x * 256 + tid;
        float vmax = -3.0e38f, vmin = 3.0e38f;
#pragma unroll
        for (int s = 0; s < 16; ++s) {
            vmax = fmaxf(vmax, pmax[s * NB + i]);
            vmin = fminf(vmin, pmin[s * NB + i]);
        }
        float sqi = sq[i];
        float ap = sqrtf(fmaxf(fmaxf(sqi + vmax, 0.0f), 1e-12f));
        float an = sqrtf(fmaxf(fmaxf(sqi + vmin, 0.0f), 1e-12f));
        float hs = fmaxf(ap - an + 0.3f, 0.0f);
        float cs = ce[i];
#pragma unroll
        for (int off = 32; off; off >>= 1) {
            hs += __shfl_xor(hs, off);
            cs += __shfl_xor(cs, off);
        }
        int wv = tid >> 6;
        if ((tid & 63) == 0) { sm.p3.sh[wv] = hs; sm.p3.sc[wv] = cs; }
        __syncthreads();
        if (tid == 0) {
            float H = sm.p3.sh[0] + sm.p3.sh[1] + sm.p3.sh[2] + sm.p3.sh[3];
            float Cs = sm.p3.sc[0] + sm.p3.sc[1] + sm.p3.sc[2] + sm.p3.sc[3];
            atomicAdd(sums + 0, H);
            atomicAdd(sums + 1, Cs);
            __threadfence();
            unsigned prev = atomicAdd(cnt, 1u);
            sm.p3.lastFlag = (prev == (unsigned)(NTAIL - 1));
        }
        __syncthreads();
        if (!sm.p3.lastFlag || tid != 0) return;

        // last block, thread 0: scalar Lambert-W tail
        double H = (double)atomicAdd(sums + 0, 0.0f);
        double Cs = (double)atomicAdd(sums + 1, 0.0f);
        const double E = 2.71828182845904523536;
        const double TAU = log(128.0);
        const double LAMd = 0.25;
        double l = H / (double)NB;
        double cev = Cs / (double)NB;
        double y = 0.5 * fmax(-2.0 / E, (l - TAU) / LAMd);
        double p = sqrt(fmax(2.0 * (E * y + 1.0), 0.0));
        double wn = -1.0 + p - p * p / 3.0 + (11.0 / 72.0) * p * p * p;
        double wlw = (y < 0.0) ? wn : log1p(fmax(y, 0.0));
#pragma unroll
        for (int it = 0; it < 10; ++it) {
            double ew = exp(wlw);
            double f = wlw * ew - y;
            double wp1 = wlw + 1.0;
            wlw = wlw - f / (ew * wp1 - (wlw + 2.0) * f / (2.0 * wp1));
        }
        double sigma = exp(-wlw);
        double lg = log(sigma);
        double loss = (cev - TAU) * sigma + LAMd * lg * lg;
        out[0] = (float)(loss / (double)NB);
    }
}

// ---------------------------------------------------------------- launcher
extern "C" void kernel_launch(void* const* d_in, const int* in_sizes, int n_in,
                              void* d_out, int out_size, void* d_ws, size_t ws_size,
                              hipStream_t stream) {
    const float* x = (const float*)d_in[0];
    const int* tgt = (const int*)d_in[1];
    float* out = (float*)d_out;

    // ws: xq (NB*128 B = 1 MB) | sq | ce | ctrl block (4 KB: sums[2], cnt,
    //     root @+128B, flag @+256B, leaf[16] @+512B, 128-B stride) | pmax | pmin
    unsigned char* xq = (unsigned char*)d_ws;
    float* sq = (float*)(xq + (size_t)NB * 128);
    float* ce = sq + NB;
    float* sums = ce + NB;                          // ctrl base
    unsigned* cnt = (unsigned*)(sums + 2);
    unsigned* ctl = (unsigned*)sums;                // word-indexed ctrl block
    float* pmax = (float*)((unsigned char*)sums + 4096);
    float* pmin = pmax + (size_t)16 * NB;

    // zero ctrl block (sums, cnt, root, flag, leaves) — poison-proof,
    // captured in the graph
    hipMemsetAsync(sums, 0, 4096, stream);
    k_fused<<<dim3(1024), dim3(256), 0, stream>>>(x, tgt, (unsigned*)xq, sq, ce, sums, cnt,
                                                  ctl, pmax, pmin, out);
}

// Round 3
// 226.429 us; speedup vs baseline: 1.5887x; 1.2796x over previous
//
#include <hip/hip_runtime.h>
#include <math.h>

#define NB 8192
#define NC 128
#define JPT 8          // j-tiles of 128 per slice

typedef float v4f __attribute__((ext_vector_type(4)));
typedef int   v8i __attribute__((ext_vector_type(8)));   // 32 fp8 (8 VGPRs)

// ---------------------------------------------------------------- ctl block
// (all 128-B line-separated; word index = line*32):
//   lines  0..63 : broadcast flags (block b polls line b&63 -> <=16 pollers/line)
//   lines 64..79 : leaf counters   (block b adds to line 64+(b&15), 64 adds, 0 readers)
//   line  80     : root counter    (16 adds, 0 readers)
//   line  87     : done counter    (128 adds, 0 readers)
//   lines 88..95 : partial sums    (line 88+(bx&7): word0=H, word1=CE; 16 adds each)
//   lines 96..223: rowcnt[bx]      (8 adds each, 0 readers)
// Round-1/2 lesson: same-line agent-scope requests serialize at the
// coherence-point bank (~110 ns each). A single polled flag line with 1024
// pollers costs a full queue pass (~113 us) to drain after the store —
// hence per-line fan-out <= 16 everywhere above.
__device__ __forceinline__ void grid_sync1(unsigned* ctl) {
    __syncthreads();
    if (threadIdx.x == 0) {
        __threadfence();   // release: this block's stores visible device-wide
        unsigned b = (unsigned)blockIdx.x;
        unsigned prev = __hip_atomic_fetch_add(ctl + (64u + (b & 15u)) * 32, 1u,
                                               __ATOMIC_ACQ_REL, __HIP_MEMORY_SCOPE_AGENT);
        if (prev == 63u) {
            unsigned pr = __hip_atomic_fetch_add(ctl + 80 * 32, 1u,
                                                 __ATOMIC_ACQ_REL, __HIP_MEMORY_SCOPE_AGENT);
            if (pr == 15u) {
                __threadfence();                 // one release fence, then relaxed stores
#pragma unroll
                for (int f = 0; f < 64; ++f)
                    __hip_atomic_store(ctl + f * 32, 1u,
                                       __ATOMIC_RELAXED, __HIP_MEMORY_SCOPE_AGENT);
            }
        }
        unsigned* myflag = ctl + (b & 63u) * 32;
        while (!__hip_atomic_load(myflag, __ATOMIC_ACQUIRE, __HIP_MEMORY_SCOPE_AGENT))
            __builtin_amdgcn_s_sleep(32);
        __threadfence();   // acquire side: refresh caches before reading peers' data
    }
    __syncthreads();
}

// ---------------------------------------------------------------- fused:
// phase 1 (prep): fp8 cast + sum-of-squares + CE term, 8 rows/block.
// barrier 1: broadcast-tree grid sync (all 1024 blocks co-resident:
//   grid = 256 CU x 4 blocks/CU, LDS 40960 x 4 = 160 KiB/CU exactly).
// phase 2 (trip): FP8 MX MFMA GEMM (64x128 tile, B double-buffered +
//   XOR-swizzled, one K=128 MFMA per 16x16 tile, fused hardest-pos/neg).
// tail: NO second grid barrier — per-row-block last-finisher chaining:
//   8 j-slice blocks share rowcnt[bx]; the 8th inlines the 64-row tail,
//   partial-sums into 8 line-separated accumulators; 128th row-block
//   winner runs the Lambert-W scalar.
__global__ __launch_bounds__(256, 4) void k_fused(const float* __restrict__ x,
                                                  const int* __restrict__ tgt,
                                                  unsigned* __restrict__ xqu,   // NB*32 uints (4 fp8 each)
                                                  float* __restrict__ sq,
                                                  float* __restrict__ ce,
                                                  unsigned* __restrict__ ctl,
                                                  float* __restrict__ pmax,     // [16][NB]
                                                  float* __restrict__ pmin,     // [16][NB]
                                                  float* __restrict__ out) {
    // Tail smem overlaid on phase-2 smem: total stays 40960 B (4 blocks/CU).
    __shared__ union {
        struct { unsigned char Bs[2][128 * 128]; float sqs[1024]; int tjs[1024]; } p2;
        struct { unsigned doTail; } p3;
    } sm;

    const int tid = threadIdx.x;

    // ---------------- phase 1: prep ----------------
    {
        int row = blockIdx.x * 8 + (tid >> 5);
        int l = tid & 31;
        float4 v = ((const float4*)(x + row * NC))[l];
        unsigned p = __builtin_amdgcn_cvt_pk_fp8_f32(v.x, v.y, 0, false);
        p = __builtin_amdgcn_cvt_pk_fp8_f32(v.z, v.w, p, true);
        xqu[row * 32 + l] = p;

        float ss = fmaf(v.x, v.x, fmaf(v.y, v.y, fmaf(v.z, v.z, v.w * v.w)));
        float mx = fmaxf(fmaxf(v.x, v.y), fmaxf(v.z, v.w));
#pragma unroll
        for (int off = 16; off; off >>= 1) {        // offsets <32: stay within half-wave
            ss += __shfl_xor(ss, off);
            mx = fmaxf(mx, __shfl_xor(mx, off));
        }
        float es = expf(v.x - mx) + expf(v.y - mx) + expf(v.z - mx) + expf(v.w - mx);
#pragma unroll
        for (int off = 16; off; off >>= 1) es += __shfl_xor(es, off);
        if (l == 0) {
            sq[row] = ss;
            ce[row] = mx + logf(es) - x[row * NC + tgt[row]];
        }
        // ctl block is zeroed by the pre-kernel memset (poison-proof).
    }

    grid_sync1(ctl);   // all xq/sq/ce visible device-wide

    // ---------------- phase 2: triplet GEMM + inlined tail ----------------
    const unsigned char* xq = (const unsigned char*)xqu;
    {
        const int lane = tid & 63;
        const int w = tid >> 6;           // wave 0..3
        const int rh = w >> 1;            // row half (32 rows)
        const int ch = w & 1;             // col half (64 cols)
        const int by = (int)blockIdx.x >> 7;      // j-slice 0..7
        const int bx = (int)blockIdx.x & 127;     // row block 0..127
        const int i0 = bx * 64;
        const int jbase = by * 1024;
        const int m = lane & 15;
        const int quad = lane >> 4;

        // ---- stage j-slice metadata via async-LDS ----
        __builtin_amdgcn_global_load_lds(
            (const __attribute__((address_space(1))) unsigned*)((const unsigned*)(sq + jbase) + (w * 64 + lane) * 4),
            (__attribute__((address_space(3))) unsigned*)(sm.p2.sqs + w * 256),
            16, 0, 0);
        __builtin_amdgcn_global_load_lds(
            (const __attribute__((address_space(1))) unsigned*)((const unsigned*)(tgt + jbase) + (w * 64 + lane) * 4),
            (__attribute__((address_space(3))) unsigned*)(sm.p2.tjs + w * 256),
            16, 0, 0);

        // ---- stage B tile 0 into buffer 0 (async) ----
#pragma unroll
        for (int c = 0; c < 4; ++c) {
            int L = w * 256 + c * 64 + lane;          // 16-B chunk index 0..1023
            int col = L >> 3, cc = L & 7;
            const unsigned char* src = xq + (size_t)(jbase + col) * 128 + ((cc ^ (col & 7)) << 4);
            __builtin_amdgcn_global_load_lds(
                (const __attribute__((address_space(1))) unsigned*)src,
                (__attribute__((address_space(3))) unsigned*)(&sm.p2.Bs[0][0] + (w * 256 + c * 64) * 16),
                16, 0, 0);
        }

        // ---- A fragments straight into registers ----
        v8i a[2];
#pragma unroll
        for (int tm = 0; tm < 2; ++tm) {
            int row = i0 + rh * 32 + tm * 16 + m;
            a[tm] = *(const v8i*)(xq + (size_t)row * 128 + quad * 32);
        }

        // ---- anchor targets for this lane's output rows ----
        int ti[2][4];
#pragma unroll
        for (int tm = 0; tm < 2; ++tm)
#pragma unroll
            for (int r = 0; r < 4; ++r)
                ti[tm][r] = tgt[i0 + rh * 32 + tm * 16 + quad * 4 + r];

        float mp[2][4], mn[2][4];
#pragma unroll
        for (int tm = 0; tm < 2; ++tm)
#pragma unroll
            for (int r = 0; r < 4; ++r) { mp[tm][r] = -3.0e38f; mn[tm][r] = 3.0e38f; }

#pragma unroll 2
        for (int jt = 0; jt < JPT; ++jt) {
            // drains the prefetch issued one full iteration ago (~free) and
            // ensures all waves are done reading the buffer we're about to fill
            __syncthreads();

            // ---- early-issue prefetch of NEXT B tile into the other buffer ----
            if (jt + 1 < JPT) {
                int jn = jbase + (jt + 1) * 128;
                unsigned char* Bnxt = &sm.p2.Bs[(jt + 1) & 1][0];
#pragma unroll
                for (int c = 0; c < 4; ++c) {
                    int L = w * 256 + c * 64 + lane;
                    int col = L >> 3, cc = L & 7;
                    const unsigned char* src = xq + (size_t)(jn + col) * 128 + ((cc ^ (col & 7)) << 4);
                    __builtin_amdgcn_global_load_lds(
                        (const __attribute__((address_space(1))) unsigned*)src,
                        (__attribute__((address_space(3))) unsigned*)(Bnxt + (w * 256 + c * 64) * 16),
                        16, 0, 0);
                }
            }

            const unsigned char* Bcur = &sm.p2.Bs[jt & 1][0];

            // ---- column metadata from LDS ----
            float sqj[4]; int tj[4];
#pragma unroll
            for (int tn = 0; tn < 4; ++tn) {
                int cloc = jt * 128 + ch * 64 + tn * 16 + m;
                sqj[tn] = sm.p2.sqs[cloc];
                tj[tn] = sm.p2.tjs[cloc];
            }

            // ---- b fragments: 32 B/lane = two b128 reads (XOR-swizzled) ----
            v8i b[4];
#pragma unroll
            for (int tn = 0; tn < 4; ++tn) {
                int col = ch * 64 + tn * 16 + m;
                int base = col * 128;
                int c0 = (((quad * 2) ^ (col & 7)) << 4);
                int c1 = (((quad * 2 + 1) ^ (col & 7)) << 4);
                *(int4*)&b[tn] = *(const int4*)(Bcur + base + c0);
                *((int4*)&b[tn] + 1) = *(const int4*)(Bcur + base + c1);
            }

            // ---- one MX MFMA per (tm,tn) covers all K=128; scales = 1.0 ----
            v4f acc[2][4];
            v4f z = {0.0f, 0.0f, 0.0f, 0.0f};
#pragma unroll
            for (int tm = 0; tm < 2; ++tm)
#pragma unroll
                for (int tn = 0; tn < 4; ++tn)
                    acc[tm][tn] = __builtin_amdgcn_mfma_scale_f32_16x16x128_f8f6f4(
                        a[tm], b[tn], z, 0, 0, 0, 0x7f7f7f7f, 0, 0x7f7f7f7f);

            // ---- fused epilogue: v = sqj - 2*dot (sqi added in tail) ----
#pragma unroll
            for (int tn = 0; tn < 4; ++tn) {
#pragma unroll
                for (int tm = 0; tm < 2; ++tm)
#pragma unroll
                    for (int r = 0; r < 4; ++r) {
                        float v = fmaf(-2.0f, acc[tm][tn][r], sqj[tn]);
                        bool pos = (tj[tn] == ti[tm][r]);
                        mp[tm][r] = fmaxf(mp[tm][r], pos ? v : -3.0e38f);
                        mn[tm][r] = fminf(mn[tm][r], pos ? 3.0e38f : v);
                    }
            }
        }

        // ---- reduce across the 16 lanes (lane&15) sharing each output row ----
#pragma unroll
        for (int off = 1; off < 16; off <<= 1) {
#pragma unroll
            for (int tm = 0; tm < 2; ++tm)
#pragma unroll
                for (int r = 0; r < 4; ++r) {
                    mp[tm][r] = fmaxf(mp[tm][r], __shfl_xor(mp[tm][r], off));
                    mn[tm][r] = fminf(mn[tm][r], __shfl_xor(mn[tm][r], off));
                }
        }
        // ---- plain stores to this wave's private (slice, row-range) ----
        if (m == 0) {
            int slice = by * 2 + ch;
            float* pm = pmax + (size_t)slice * NB + i0 + rh * 32;
            float* pn = pmin + (size_t)slice * NB + i0 + rh * 32;
#pragma unroll
            for (int tm = 0; tm < 2; ++tm)
#pragma unroll
                for (int r = 0; r < 4; ++r) {
                    int rr = tm * 16 + quad * 4 + r;
                    pm[rr] = mp[tm][r];
                    pn[rr] = mn[tm][r];
                }
        }

        // ---- last-finisher chaining: 8th block for this bx inlines the tail ----
        __syncthreads();              // all this block's pmax/pmin stores done
        if (tid == 0) {
            __threadfence();          // release our slice results
            unsigned prev = __hip_atomic_fetch_add(ctl + (96u + (unsigned)bx) * 32, 1u,
                                                   __ATOMIC_ACQ_REL, __HIP_MEMORY_SCOPE_AGENT);
            sm.p3.doTail = (prev == 7u);
        }
        __syncthreads();
        if (!sm.p3.doTail) return;

        if (tid < 64) {               // wave 0 handles rows i0..i0+63
            __threadfence();          // acquire: peers' pmax/pmin from MALL
            int i = i0 + tid;
            float vmax = -3.0e38f, vmin = 3.0e38f;
#pragma unroll
            for (int s = 0; s < 16; ++s) {
                vmax = fmaxf(vmax, pmax[s * NB + i]);
                vmin = fminf(vmin, pmin[s * NB + i]);
            }
            float sqi = sq[i];
            float ap = sqrtf(fmaxf(fmaxf(sqi + vmax, 0.0f), 1e-12f));
            float an = sqrtf(fmaxf(fmaxf(sqi + vmin, 0.0f), 1e-12f));
            float hs = fmaxf(ap - an + 0.3f, 0.0f);
            float cs = ce[i];
#pragma unroll
            for (int off = 32; off; off >>= 1) {
                hs += __shfl_xor(hs, off);
                cs += __shfl_xor(cs, off);
            }
            if (tid == 0) {
                float* pl = (float*)(ctl + (88u + (unsigned)(bx & 7)) * 32);
                atomicAdd(pl + 0, hs);
                atomicAdd(pl + 1, cs);
                __threadfence();
                unsigned prev2 = __hip_atomic_fetch_add(ctl + 87 * 32, 1u,
                                                        __ATOMIC_ACQ_REL, __HIP_MEMORY_SCOPE_AGENT);
                if (prev2 == 127u) {
                    // very last finisher: scalar Lambert-W tail
                    double H = 0.0, Cs = 0.0;
#pragma unroll
                    for (int k = 0; k < 8; ++k) {
                        float* q = (float*)(ctl + (88u + (unsigned)k) * 32);
                        H  += (double)atomicAdd(q + 0, 0.0f);
                        Cs += (double)atomicAdd(q + 1, 0.0f);
                    }
                    const double E = 2.71828182845904523536;
                    const double TAU = log(128.0);
                    const double LAMd = 0.25;
                    double l = H / (double)NB;
                    double cev = Cs / (double)NB;
                    double y = 0.5 * fmax(-2.0 / E, (l - TAU) / LAMd);
                    double p = sqrt(fmax(2.0 * (E * y + 1.0), 0.0));
                    double wn = -1.0 + p - p * p / 3.0 + (11.0 / 72.0) * p * p * p;
                    double wlw = (y < 0.0) ? wn : log1p(fmax(y, 0.0));
#pragma unroll
                    for (int it = 0; it < 10; ++it) {
                        double ew = exp(wlw);
                        double f = wlw * ew - y;
                        double wp1 = wlw + 1.0;
                        wlw = wlw - f / (ew * wp1 - (wlw + 2.0) * f / (2.0 * wp1));
                    }
                    double sigma = exp(-wlw);
                    double lg = log(sigma);
                    double loss = (cev - TAU) * sigma + LAMd * lg * lg;
                    out[0] = (float)(loss / (double)NB);
                }
            }
        }
    }
}

// ---------------------------------------------------------------- launcher
extern "C" void kernel_launch(void* const* d_in, const int* in_sizes, int n_in,
                              void* d_out, int out_size, void* d_ws, size_t ws_size,
                              hipStream_t stream) {
    const float* x = (const float*)d_in[0];
    const int* tgt = (const int*)d_in[1];
    float* out = (float*)d_out;

    // ws: xq (1 MB) | sq (32 KB) | ce (32 KB) | ctl (32 KB) | pmax | pmin
    unsigned char* xq = (unsigned char*)d_ws;
    float* sq = (float*)(xq + (size_t)NB * 128);
    float* ce = sq + NB;
    unsigned* ctl = (unsigned*)(ce + NB);
    float* pmax = (float*)((unsigned char*)ctl + 32768);
    float* pmin = pmax + (size_t)16 * NB;

    // zero ctl block (flags, counters, partial sums) — poison-proof
    hipMemsetAsync(ctl, 0, 32768, stream);
    k_fused<<<dim3(1024), dim3(256), 0, stream>>>(x, tgt, (unsigned*)xq, sq, ce,
                                                  ctl, pmax, pmin, out);
}

// Round 4
// 124.046 us; speedup vs baseline: 2.8999x; 1.8254x over previous
//
#include <hip/hip_runtime.h>
#include <math.h>

#define NB 8192
#define NC 128
#define NJS 8          // j-slices (grid.y); slice = 1024 cols
#define JPT 8          // j-tiles of 128 per slice

typedef float v4f __attribute__((ext_vector_type(4)));
typedef int   v8i __attribute__((ext_vector_type(8)));   // 32 fp8 (8 VGPRs)

// ---------------------------------------------------------------- ctl block
// (128-B line-separated; word index = line*32). Zeroed by k_prep block 0
// (prep completes before trip starts -> safe, and saves a memset dispatch).
//   line  0      : done counter   (128 adds, 0 readers)
//   lines 8..15  : partial sums   (line 8+(bx&7): word0=H, word1=CE; 16 adds each)
//   lines 16..143: rowcnt[bx]     (8 adds each, 0 readers)
// Rounds 1-3 lesson: grid-wide sync costs 150+ us on this chip regardless of
// flag fan-out (fence/invalidate storm), but last-finisher CHAINING is cheap
// (R2->R3: -54 us) and bit-exact. So: dispatch boundary for the all-to-all
// prep->trip dependency; chaining for trip->tail.

// ---------------------------------------------------------------- prep:
// per row: fp8 e4m3 cast (packed 4/lane), sum-of-squares (fp32), CE term
// (fp32). 8 rows per 256-thr block, 32 lanes per row. Block 0 also zeroes
// the ctl block.
__global__ __launch_bounds__(256) void k_prep(const float* __restrict__ x,
                                              const int* __restrict__ tgt,
                                              unsigned* __restrict__ xq,   // NB*32 uints (4 fp8 each)
                                              float* __restrict__ sq,
                                              float* __restrict__ ce,
                                              unsigned* __restrict__ ctl) {
    int row = blockIdx.x * 8 + (threadIdx.x >> 5);
    int l = threadIdx.x & 31;
    float4 v = ((const float4*)(x + row * NC))[l];
    unsigned p = __builtin_amdgcn_cvt_pk_fp8_f32(v.x, v.y, 0, false);
    p = __builtin_amdgcn_cvt_pk_fp8_f32(v.z, v.w, p, true);
    xq[row * 32 + l] = p;

    float ss = fmaf(v.x, v.x, fmaf(v.y, v.y, fmaf(v.z, v.z, v.w * v.w)));
    float mx = fmaxf(fmaxf(v.x, v.y), fmaxf(v.z, v.w));
#pragma unroll
    for (int off = 16; off; off >>= 1) {        // offsets <32: stay within half-wave
        ss += __shfl_xor(ss, off);
        mx = fmaxf(mx, __shfl_xor(mx, off));
    }
    float es = expf(v.x - mx) + expf(v.y - mx) + expf(v.z - mx) + expf(v.w - mx);
#pragma unroll
    for (int off = 16; off; off >>= 1) es += __shfl_xor(es, off);
    if (l == 0) {
        sq[row] = ss;
        ce[row] = mx + logf(es) - x[row * NC + tgt[row]];
    }
    // zero ctl (32 KB): 256 threads x 2 uint4-stores x ... (2048 uint4 total)
    if (blockIdx.x == 0) {
        uint4 zz = {0u, 0u, 0u, 0u};
#pragma unroll
        for (int k = 0; k < 8; ++k)
            ((uint4*)ctl)[threadIdx.x + k * 256] = zz;
    }
}

// ---------------------------------------------------------------- trip:
// FP8 E4M3 MX-scaled MFMA GEMM (16x16x128_f8f6f4, unit E8M0 scales -> plain
// fp8 dot at 2x the non-scaled rate; ONE MFMA covers K=128). 64x128 block
// tile (wave = 32x64), A in regs, B double-buffered (2 x 16 KB) + metadata
// (8 KB) = 40 KB LDS => 4 blocks/CU. B staged with 16-B chunk XOR swizzle
// on the GLOBAL source address; b-frag = two ds_read_b128 at physical chunk
// (logical ^ (col&7)) — full LDS BW. Tail is CHAINED: the 8th j-slice
// finisher per row-block inlines the 64-row hinge+CE reduction; the 128th
// row-block winner runs the Lambert-W scalar. No grid barrier anywhere.
__global__ __launch_bounds__(256, 4) void k_trip(const unsigned char* __restrict__ xq,
                                                 const int* __restrict__ tgt,
                                                 const float* __restrict__ sq,
                                                 const float* __restrict__ ce,
                                                 unsigned* __restrict__ ctl,
                                                 float* __restrict__ pmax,   // [16][NB]
                                                 float* __restrict__ pmin,   // [16][NB]
                                                 float* __restrict__ out) {
    __shared__ union {
        struct { unsigned char Bs[2][128 * 128]; float sqs[1024]; int tjs[1024]; } p2;
        struct { unsigned doTail; } p3;
    } sm;

    const int tid = threadIdx.x;
    const int lane = tid & 63;
    const int w = tid >> 6;           // wave 0..3
    const int rh = w >> 1;            // row half (32 rows)
    const int ch = w & 1;             // col half (64 cols)
    const int bx = (int)blockIdx.x;           // row block 0..127
    const int by = (int)blockIdx.y;           // j-slice 0..7
    const int i0 = bx * 64;
    const int jbase = by * 1024;
    const int m = lane & 15;
    const int quad = lane >> 4;

    // ---- stage j-slice metadata via async-LDS ----
    __builtin_amdgcn_global_load_lds(
        (const __attribute__((address_space(1))) unsigned*)((const unsigned*)(sq + jbase) + (w * 64 + lane) * 4),
        (__attribute__((address_space(3))) unsigned*)(sm.p2.sqs + w * 256),
        16, 0, 0);
    __builtin_amdgcn_global_load_lds(
        (const __attribute__((address_space(1))) unsigned*)((const unsigned*)(tgt + jbase) + (w * 64 + lane) * 4),
        (__attribute__((address_space(3))) unsigned*)(sm.p2.tjs + w * 256),
        16, 0, 0);

    // ---- stage B tile 0 into buffer 0 (async) ----
#pragma unroll
    for (int c = 0; c < 4; ++c) {
        int L = w * 256 + c * 64 + lane;          // 16-B chunk index 0..1023
        int col = L >> 3, cc = L & 7;
        const unsigned char* src = xq + (size_t)(jbase + col) * 128 + ((cc ^ (col & 7)) << 4);
        __builtin_amdgcn_global_load_lds(
            (const __attribute__((address_space(1))) unsigned*)src,
            (__attribute__((address_space(3))) unsigned*)(&sm.p2.Bs[0][0] + (w * 256 + c * 64) * 16),
            16, 0, 0);
    }

    // ---- A fragments straight into registers (32 B/frag, once per block) ----
    v8i a[2];
#pragma unroll
    for (int tm = 0; tm < 2; ++tm) {
        int row = i0 + rh * 32 + tm * 16 + m;
        a[tm] = *(const v8i*)(xq + (size_t)row * 128 + quad * 32);
    }

    // ---- anchor targets for this lane's output rows ----
    int ti[2][4];
#pragma unroll
    for (int tm = 0; tm < 2; ++tm)
#pragma unroll
        for (int r = 0; r < 4; ++r)
            ti[tm][r] = tgt[i0 + rh * 32 + tm * 16 + quad * 4 + r];

    float mp[2][4], mn[2][4];
#pragma unroll
    for (int tm = 0; tm < 2; ++tm)
#pragma unroll
        for (int r = 0; r < 4; ++r) { mp[tm][r] = -3.0e38f; mn[tm][r] = 3.0e38f; }

#pragma unroll 2
    for (int jt = 0; jt < JPT; ++jt) {
        // drains the prefetch issued one full iteration ago (~free) and
        // ensures all waves are done reading the buffer we're about to fill
        __syncthreads();

        // ---- early-issue prefetch of NEXT B tile into the other buffer ----
        if (jt + 1 < JPT) {
            int jn = jbase + (jt + 1) * 128;
            unsigned char* Bnxt = &sm.p2.Bs[(jt + 1) & 1][0];
#pragma unroll
            for (int c = 0; c < 4; ++c) {
                int L = w * 256 + c * 64 + lane;
                int col = L >> 3, cc = L & 7;
                const unsigned char* src = xq + (size_t)(jn + col) * 128 + ((cc ^ (col & 7)) << 4);
                __builtin_amdgcn_global_load_lds(
                    (const __attribute__((address_space(1))) unsigned*)src,
                    (__attribute__((address_space(3))) unsigned*)(Bnxt + (w * 256 + c * 64) * 16),
                    16, 0, 0);
            }
        }

        const unsigned char* Bcur = &sm.p2.Bs[jt & 1][0];

        // ---- column metadata from LDS ----
        float sqj[4]; int tj[4];
#pragma unroll
        for (int tn = 0; tn < 4; ++tn) {
            int cloc = jt * 128 + ch * 64 + tn * 16 + m;
            sqj[tn] = sm.p2.sqs[cloc];
            tj[tn] = sm.p2.tjs[cloc];
        }

        // ---- b fragments: 32 B/lane = two b128 reads (XOR-swizzled) ----
        v8i b[4];
#pragma unroll
        for (int tn = 0; tn < 4; ++tn) {
            int col = ch * 64 + tn * 16 + m;
            int base = col * 128;
            int c0 = (((quad * 2) ^ (col & 7)) << 4);
            int c1 = (((quad * 2 + 1) ^ (col & 7)) << 4);
            *(int4*)&b[tn] = *(const int4*)(Bcur + base + c0);
            *((int4*)&b[tn] + 1) = *(const int4*)(Bcur + base + c1);
        }

        // ---- one MX MFMA per (tm,tn) covers all K=128; scales = 1.0 ----
        v4f acc[2][4];
        v4f z = {0.0f, 0.0f, 0.0f, 0.0f};
#pragma unroll
        for (int tm = 0; tm < 2; ++tm)
#pragma unroll
            for (int tn = 0; tn < 4; ++tn)
                acc[tm][tn] = __builtin_amdgcn_mfma_scale_f32_16x16x128_f8f6f4(
                    a[tm], b[tn], z, 0, 0, 0, 0x7f7f7f7f, 0, 0x7f7f7f7f);

        // ---- fused epilogue: v = sqj - 2*dot (sqi added in tail) ----
#pragma unroll
        for (int tn = 0; tn < 4; ++tn) {
#pragma unroll
            for (int tm = 0; tm < 2; ++tm)
#pragma unroll
                for (int r = 0; r < 4; ++r) {
                    float v = fmaf(-2.0f, acc[tm][tn][r], sqj[tn]);
                    bool pos = (tj[tn] == ti[tm][r]);
                    mp[tm][r] = fmaxf(mp[tm][r], pos ? v : -3.0e38f);
                    mn[tm][r] = fminf(mn[tm][r], pos ? 3.0e38f : v);
                }
        }
    }

    // ---- reduce across the 16 lanes (lane&15) sharing each output row ----
#pragma unroll
    for (int off = 1; off < 16; off <<= 1) {
#pragma unroll
        for (int tm = 0; tm < 2; ++tm)
#pragma unroll
            for (int r = 0; r < 4; ++r) {
                mp[tm][r] = fmaxf(mp[tm][r], __shfl_xor(mp[tm][r], off));
                mn[tm][r] = fminf(mn[tm][r], __shfl_xor(mn[tm][r], off));
            }
    }
    // ---- plain stores to this wave's private (slice, row-range) ----
    if (m == 0) {
        int slice = by * 2 + ch;
        float* pm = pmax + (size_t)slice * NB + i0 + rh * 32;
        float* pn = pmin + (size_t)slice * NB + i0 + rh * 32;
#pragma unroll
        for (int tm = 0; tm < 2; ++tm)
#pragma unroll
            for (int r = 0; r < 4; ++r) {
                int rr = tm * 16 + quad * 4 + r;
                pm[rr] = mp[tm][r];
                pn[rr] = mn[tm][r];
            }
    }

    // ---- last-finisher chaining: 8th j-slice block for this bx runs tail ----
    __syncthreads();              // all this block's pmax/pmin stores issued
    if (tid == 0) {
        __threadfence();          // release our slice results device-wide
        unsigned prev = __hip_atomic_fetch_add(ctl + (16u + (unsigned)bx) * 32, 1u,
                                               __ATOMIC_ACQ_REL, __HIP_MEMORY_SCOPE_AGENT);
        sm.p3.doTail = (prev == 7u);
    }
    __syncthreads();
    if (!sm.p3.doTail) return;

    if (tid < 64) {               // wave 0 handles rows i0..i0+63
        __threadfence();          // acquire: peers' pmax/pmin from coherence point
        int i = i0 + tid;
        float vmax = -3.0e38f, vmin = 3.0e38f;
#pragma unroll
        for (int s = 0; s < 16; ++s) {
            vmax = fmaxf(vmax, pmax[s * NB + i]);
            vmin = fminf(vmin, pmin[s * NB + i]);
        }
        float sqi = sq[i];
        float ap = sqrtf(fmaxf(fmaxf(sqi + vmax, 0.0f), 1e-12f));
        float an = sqrtf(fmaxf(fmaxf(sqi + vmin, 0.0f), 1e-12f));
        float hs = fmaxf(ap - an + 0.3f, 0.0f);
        float cs = ce[i];
#pragma unroll
        for (int off = 32; off; off >>= 1) {
            hs += __shfl_xor(hs, off);
            cs += __shfl_xor(cs, off);
        }
        if (tid == 0) {
            float* pl = (float*)(ctl + (8u + (unsigned)(bx & 7)) * 32);
            atomicAdd(pl + 0, hs);
            atomicAdd(pl + 1, cs);
            __threadfence();
            unsigned prev2 = __hip_atomic_fetch_add(ctl + 0, 1u,
                                                    __ATOMIC_ACQ_REL, __HIP_MEMORY_SCOPE_AGENT);
            if (prev2 == 127u) {
                // very last finisher: scalar Lambert-W tail
                double H = 0.0, Cs = 0.0;
#pragma unroll
                for (int k = 0; k < 8; ++k) {
                    float* q = (float*)(ctl + (8u + (unsigned)k) * 32);
                    H  += (double)atomicAdd(q + 0, 0.0f);
                    Cs += (double)atomicAdd(q + 1, 0.0f);
                }
                const double E = 2.71828182845904523536;
                const double TAU = log(128.0);
                const double LAMd = 0.25;
                double l = H / (double)NB;
                double cev = Cs / (double)NB;
                double y = 0.5 * fmax(-2.0 / E, (l - TAU) / LAMd);
                double p = sqrt(fmax(2.0 * (E * y + 1.0), 0.0));
                double wn = -1.0 + p - p * p / 3.0 + (11.0 / 72.0) * p * p * p;
                double wlw = (y < 0.0) ? wn : log1p(fmax(y, 0.0));
#pragma unroll
                for (int it = 0; it < 10; ++it) {
                    double ew = exp(wlw);
                    double f = wlw * ew - y;
                    double wp1 = wlw + 1.0;
                    wlw = wlw - f / (ew * wp1 - (wlw + 2.0) * f / (2.0 * wp1));
                }
                double sigma = exp(-wlw);
                double lg = log(sigma);
                double loss = (cev - TAU) * sigma + LAMd * lg * lg;
                out[0] = (float)(loss / (double)NB);
            }
        }
    }
}

// ---------------------------------------------------------------- launcher
extern "C" void kernel_launch(void* const* d_in, const int* in_sizes, int n_in,
                              void* d_out, int out_size, void* d_ws, size_t ws_size,
                              hipStream_t stream) {
    const float* x = (const float*)d_in[0];
    const int* tgt = (const int*)d_in[1];
    float* out = (float*)d_out;

    // ws: xq (1 MB) | sq (32 KB) | ce (32 KB) | ctl (32 KB) | pmax | pmin
    unsigned char* xq = (unsigned char*)d_ws;
    float* sq = (float*)(xq + (size_t)NB * 128);
    float* ce = sq + NB;
    unsigned* ctl = (unsigned*)(ce + NB);
    float* pmax = (float*)((unsigned char*)ctl + 32768);
    float* pmin = pmax + (size_t)16 * NB;

    k_prep<<<NB / 8, 256, 0, stream>>>(x, tgt, (unsigned*)xq, sq, ce, ctl);
    dim3 grid(NB / 64, NJS);
    k_trip<<<grid, 256, 0, stream>>>(xq, tgt, sq, ce, ctl, pmax, pmin, out);
}

// Round 5
// 86.644 us; speedup vs baseline: 4.1517x; 1.4317x over previous
//
#include <hip/hip_runtime.h>
#include <math.h>

#define NB 8192
#define NC 128
#define NJS 8          // j-slices (grid.y); slice = 1024 cols
#define JPT 8          // j-tiles of 128 per slice

typedef float v4f __attribute__((ext_vector_type(4)));
typedef int   v8i __attribute__((ext_vector_type(8)));   // 32 fp8 (8 VGPRs)

// ---------------------------------------------------------------- ctl block
// (128-B line-separated; word index = line*32). Zeroed by k_prep block 0.
//   line  0      : done counter   (128 adds, 0 readers)
//   lines 8..15  : partial sums   (line 8+(bx&7): word0=H, word1=CE)
//   lines 16..143: rowcnt[bx]     (8 adds each, 0 readers)
//
// R1-R4 lesson chain: grid barriers cost 150+ us NOT because of polling but
// because each __threadfence() at agent scope is a BULK L2 writeback
// (buffer_wbl2) / invalidate (buffer_inv); 1024 of them serialize at the
// per-XCD L2 (~0.35 us each). R4's A/B: chained tail + 2 fences/block took
// k_trip 27 -> 73.7 us. So: NO fences anywhere. Cross-XCD visibility is done
// per-access: results stored with RELAXED/AGENT atomics (global_store sc0 sc1,
// write-through to MALL), read with RELAXED/AGENT atomic loads (read at MALL).
// __syncthreads() drains vmcnt (compiler emits s_waitcnt vmcnt(0) before
// s_barrier), so a RELAXED rowcnt RMW after it is a correct release-by-
// construction; atomic->atomic ordering uses a raw s_waitcnt vmcnt(0).

// ---------------------------------------------------------------- prep:
// per row: fp8 e4m3 cast (packed 4/lane), sum-of-squares (fp32), CE term
// (fp32). 8 rows per 256-thr block, 32 lanes per row. Block 0 zeroes ctl.
__global__ __launch_bounds__(256) void k_prep(const float* __restrict__ x,
                                              const int* __restrict__ tgt,
                                              unsigned* __restrict__ xq,   // NB*32 uints (4 fp8 each)
                                              float* __restrict__ sq,
                                              float* __restrict__ ce,
                                              unsigned* __restrict__ ctl) {
    int row = blockIdx.x * 8 + (threadIdx.x >> 5);
    int l = threadIdx.x & 31;
    float4 v = ((const float4*)(x + row * NC))[l];
    unsigned p = __builtin_amdgcn_cvt_pk_fp8_f32(v.x, v.y, 0, false);
    p = __builtin_amdgcn_cvt_pk_fp8_f32(v.z, v.w, p, true);
    xq[row * 32 + l] = p;

    float ss = fmaf(v.x, v.x, fmaf(v.y, v.y, fmaf(v.z, v.z, v.w * v.w)));
    float mx = fmaxf(fmaxf(v.x, v.y), fmaxf(v.z, v.w));
#pragma unroll
    for (int off = 16; off; off >>= 1) {        // offsets <32: stay within half-wave
        ss += __shfl_xor(ss, off);
        mx = fmaxf(mx, __shfl_xor(mx, off));
    }
    float es = expf(v.x - mx) + expf(v.y - mx) + expf(v.z - mx) + expf(v.w - mx);
#pragma unroll
    for (int off = 16; off; off >>= 1) es += __shfl_xor(es, off);
    if (l == 0) {
        sq[row] = ss;
        ce[row] = mx + logf(es) - x[row * NC + tgt[row]];
    }
    // zero ctl (32 KB): 256 threads x 8 uint4-stores
    if (blockIdx.x == 0) {
        uint4 zz = {0u, 0u, 0u, 0u};
#pragma unroll
        for (int k = 0; k < 8; ++k)
            ((uint4*)ctl)[threadIdx.x + k * 256] = zz;
    }
}

// ---------------------------------------------------------------- trip:
// FP8 E4M3 MX-scaled MFMA GEMM (16x16x128_f8f6f4, unit E8M0 scales; ONE MFMA
// covers K=128). 64x128 block tile, A in regs, B double-buffered (2 x 16 KB)
// + metadata (8 KB) = 40 KB LDS => 4 blocks/CU. B staged with 16-B chunk XOR
// swizzle on the GLOBAL source address; b-frag = two ds_read_b128 at physical
// chunk (logical ^ (col&7)). Tail CHAINED fence-free: results written through
// to MALL with relaxed agent stores; 8th j-slice finisher per row-block
// inlines the 64-row hinge+CE reduction; 128th row-block winner runs
// Lambert-W. No grid barrier, no threadfence anywhere.
__global__ __launch_bounds__(256, 4) void k_trip(const unsigned char* __restrict__ xq,
                                                 const int* __restrict__ tgt,
                                                 const float* __restrict__ sq,
                                                 const float* __restrict__ ce,
                                                 unsigned* __restrict__ ctl,
                                                 float* __restrict__ pmax,   // [16][NB]
                                                 float* __restrict__ pmin,   // [16][NB]
                                                 float* __restrict__ out) {
    __shared__ union {
        struct { unsigned char Bs[2][128 * 128]; float sqs[1024]; int tjs[1024]; } p2;
        struct { unsigned doTail; } p3;
    } sm;

    const int tid = threadIdx.x;
    const int lane = tid & 63;
    const int w = tid >> 6;           // wave 0..3
    const int rh = w >> 1;            // row half (32 rows)
    const int ch = w & 1;             // col half (64 cols)
    const int bx = (int)blockIdx.x;           // row block 0..127
    const int by = (int)blockIdx.y;           // j-slice 0..7
    const int i0 = bx * 64;
    const int jbase = by * 1024;
    const int m = lane & 15;
    const int quad = lane >> 4;

    // ---- stage j-slice metadata via async-LDS ----
    __builtin_amdgcn_global_load_lds(
        (const __attribute__((address_space(1))) unsigned*)((const unsigned*)(sq + jbase) + (w * 64 + lane) * 4),
        (__attribute__((address_space(3))) unsigned*)(sm.p2.sqs + w * 256),
        16, 0, 0);
    __builtin_amdgcn_global_load_lds(
        (const __attribute__((address_space(1))) unsigned*)((const unsigned*)(tgt + jbase) + (w * 64 + lane) * 4),
        (__attribute__((address_space(3))) unsigned*)(sm.p2.tjs + w * 256),
        16, 0, 0);

    // ---- stage B tile 0 into buffer 0 (async) ----
#pragma unroll
    for (int c = 0; c < 4; ++c) {
        int L = w * 256 + c * 64 + lane;          // 16-B chunk index 0..1023
        int col = L >> 3, cc = L & 7;
        const unsigned char* src = xq + (size_t)(jbase + col) * 128 + ((cc ^ (col & 7)) << 4);
        __builtin_amdgcn_global_load_lds(
            (const __attribute__((address_space(1))) unsigned*)src,
            (__attribute__((address_space(3))) unsigned*)(&sm.p2.Bs[0][0] + (w * 256 + c * 64) * 16),
            16, 0, 0);
    }

    // ---- A fragments straight into registers (32 B/frag, once per block) ----
    v8i a[2];
#pragma unroll
    for (int tm = 0; tm < 2; ++tm) {
        int row = i0 + rh * 32 + tm * 16 + m;
        a[tm] = *(const v8i*)(xq + (size_t)row * 128 + quad * 32);
    }

    // ---- anchor targets for this lane's output rows ----
    int ti[2][4];
#pragma unroll
    for (int tm = 0; tm < 2; ++tm)
#pragma unroll
        for (int r = 0; r < 4; ++r)
            ti[tm][r] = tgt[i0 + rh * 32 + tm * 16 + quad * 4 + r];

    float mp[2][4], mn[2][4];
#pragma unroll
    for (int tm = 0; tm < 2; ++tm)
#pragma unroll
        for (int r = 0; r < 4; ++r) { mp[tm][r] = -3.0e38f; mn[tm][r] = 3.0e38f; }

#pragma unroll 2
    for (int jt = 0; jt < JPT; ++jt) {
        // drains the prefetch issued one full iteration ago (~free) and
        // ensures all waves are done reading the buffer we're about to fill
        __syncthreads();

        // ---- early-issue prefetch of NEXT B tile into the other buffer ----
        if (jt + 1 < JPT) {
            int jn = jbase + (jt + 1) * 128;
            unsigned char* Bnxt = &sm.p2.Bs[(jt + 1) & 1][0];
#pragma unroll
            for (int c = 0; c < 4; ++c) {
                int L = w * 256 + c * 64 + lane;
                int col = L >> 3, cc = L & 7;
                const unsigned char* src = xq + (size_t)(jn + col) * 128 + ((cc ^ (col & 7)) << 4);
                __builtin_amdgcn_global_load_lds(
                    (const __attribute__((address_space(1))) unsigned*)src,
                    (__attribute__((address_space(3))) unsigned*)(Bnxt + (w * 256 + c * 64) * 16),
                    16, 0, 0);
            }
        }

        const unsigned char* Bcur = &sm.p2.Bs[jt & 1][0];

        // ---- column metadata from LDS ----
        float sqj[4]; int tj[4];
#pragma unroll
        for (int tn = 0; tn < 4; ++tn) {
            int cloc = jt * 128 + ch * 64 + tn * 16 + m;
            sqj[tn] = sm.p2.sqs[cloc];
            tj[tn] = sm.p2.tjs[cloc];
        }

        // ---- b fragments: 32 B/lane = two b128 reads (XOR-swizzled) ----
        v8i b[4];
#pragma unroll
        for (int tn = 0; tn < 4; ++tn) {
            int col = ch * 64 + tn * 16 + m;
            int base = col * 128;
            int c0 = (((quad * 2) ^ (col & 7)) << 4);
            int c1 = (((quad * 2 + 1) ^ (col & 7)) << 4);
            *(int4*)&b[tn] = *(const int4*)(Bcur + base + c0);
            *((int4*)&b[tn] + 1) = *(const int4*)(Bcur + base + c1);
        }

        // ---- one MX MFMA per (tm,tn) covers all K=128; scales = 1.0 ----
        v4f acc[2][4];
        v4f z = {0.0f, 0.0f, 0.0f, 0.0f};
#pragma unroll
        for (int tm = 0; tm < 2; ++tm)
#pragma unroll
            for (int tn = 0; tn < 4; ++tn)
                acc[tm][tn] = __builtin_amdgcn_mfma_scale_f32_16x16x128_f8f6f4(
                    a[tm], b[tn], z, 0, 0, 0, 0x7f7f7f7f, 0, 0x7f7f7f7f);

        // ---- fused epilogue: v = sqj - 2*dot (sqi added in tail) ----
#pragma unroll
        for (int tn = 0; tn < 4; ++tn) {
#pragma unroll
            for (int tm = 0; tm < 2; ++tm)
#pragma unroll
                for (int r = 0; r < 4; ++r) {
                    float v = fmaf(-2.0f, acc[tm][tn][r], sqj[tn]);
                    bool pos = (tj[tn] == ti[tm][r]);
                    mp[tm][r] = fmaxf(mp[tm][r], pos ? v : -3.0e38f);
                    mn[tm][r] = fminf(mn[tm][r], pos ? 3.0e38f : v);
                }
        }
    }

    // ---- reduce across the 16 lanes (lane&15) sharing each output row ----
#pragma unroll
    for (int off = 1; off < 16; off <<= 1) {
#pragma unroll
        for (int tm = 0; tm < 2; ++tm)
#pragma unroll
            for (int r = 0; r < 4; ++r) {
                mp[tm][r] = fmaxf(mp[tm][r], __shfl_xor(mp[tm][r], off));
                mn[tm][r] = fminf(mn[tm][r], __shfl_xor(mn[tm][r], off));
            }
    }
    // ---- write-through stores (relaxed agent -> sc0 sc1, MALL-visible) ----
    if (m == 0) {
        int slice = by * 2 + ch;
        float* pm = pmax + (size_t)slice * NB + i0 + rh * 32;
        float* pn = pmin + (size_t)slice * NB + i0 + rh * 32;
#pragma unroll
        for (int tm = 0; tm < 2; ++tm)
#pragma unroll
            for (int r = 0; r < 4; ++r) {
                int rr = tm * 16 + quad * 4 + r;
                __hip_atomic_store(pm + rr, mp[tm][r], __ATOMIC_RELAXED, __HIP_MEMORY_SCOPE_AGENT);
                __hip_atomic_store(pn + rr, mn[tm][r], __ATOMIC_RELAXED, __HIP_MEMORY_SCOPE_AGENT);
            }
    }

    // ---- last-finisher chaining, FENCE-FREE ----
    // __syncthreads() semantics drain every wave's vmcnt before s_barrier;
    // the sc0/sc1 stores above are then already at the coherence point, so a
    // RELAXED rowcnt RMW is a correct release here (no buffer_wbl2 emitted).
    __syncthreads();
    if (tid == 0) {
        unsigned prev = __hip_atomic_fetch_add(ctl + (16u + (unsigned)bx) * 32, 1u,
                                               __ATOMIC_RELAXED, __HIP_MEMORY_SCOPE_AGENT);
        sm.p3.doTail = (prev == 7u);
    }
    __syncthreads();
    if (!sm.p3.doTail) return;

    if (tid < 64) {               // wave 0 handles rows i0..i0+63
        int i = i0 + tid;
        float vmax = -3.0e38f, vmin = 3.0e38f;
#pragma unroll
        for (int s = 0; s < 16; ++s) {     // relaxed agent loads: read at MALL, no buffer_inv
            vmax = fmaxf(vmax, __hip_atomic_load(pmax + (size_t)s * NB + i,
                                                 __ATOMIC_RELAXED, __HIP_MEMORY_SCOPE_AGENT));
            vmin = fminf(vmin, __hip_atomic_load(pmin + (size_t)s * NB + i,
                                                 __ATOMIC_RELAXED, __HIP_MEMORY_SCOPE_AGENT));
        }
        float sqi = sq[i];
        float ap = sqrtf(fmaxf(fmaxf(sqi + vmax, 0.0f), 1e-12f));
        float an = sqrtf(fmaxf(fmaxf(sqi + vmin, 0.0f), 1e-12f));
        float hs = fmaxf(ap - an + 0.3f, 0.0f);
        float cs = ce[i];
#pragma unroll
        for (int off = 32; off; off >>= 1) {
            hs += __shfl_xor(hs, off);
            cs += __shfl_xor(cs, off);
        }
        if (tid == 0) {
            float* pl = (float*)(ctl + (8u + (unsigned)(bx & 7)) * 32);
            atomicAdd(pl + 0, hs);
            atomicAdd(pl + 1, cs);
            // order the two adds before the done-RMW without a bulk fence:
            asm volatile("s_waitcnt vmcnt(0)" ::: "memory");
            unsigned prev2 = __hip_atomic_fetch_add(ctl + 0, 1u,
                                                    __ATOMIC_RELAXED, __HIP_MEMORY_SCOPE_AGENT);
            if (prev2 == 127u) {
                // very last finisher: scalar Lambert-W tail
                double H = 0.0, Cs = 0.0;
#pragma unroll
                for (int k = 0; k < 8; ++k) {
                    float* q = (float*)(ctl + (8u + (unsigned)k) * 32);
                    H  += (double)atomicAdd(q + 0, 0.0f);
                    Cs += (double)atomicAdd(q + 1, 0.0f);
                }
                const double E = 2.71828182845904523536;
                const double TAU = log(128.0);
                const double LAMd = 0.25;
                double l = H / (double)NB;
                double cev = Cs / (double)NB;
                double y = 0.5 * fmax(-2.0 / E, (l - TAU) / LAMd);
                double p = sqrt(fmax(2.0 * (E * y + 1.0), 0.0));
                double wn = -1.0 + p - p * p / 3.0 + (11.0 / 72.0) * p * p * p;
                double wlw = (y < 0.0) ? wn : log1p(fmax(y, 0.0));
#pragma unroll
                for (int it = 0; it < 10; ++it) {
                    double ew = exp(wlw);
                    double f = wlw * ew - y;
                    double wp1 = wlw + 1.0;
                    wlw = wlw - f / (ew * wp1 - (wlw + 2.0) * f / (2.0 * wp1));
                }
                double sigma = exp(-wlw);
                double lg = log(sigma);
                double loss = (cev - TAU) * sigma + LAMd * lg * lg;
                out[0] = (float)(loss / (double)NB);
            }
        }
    }
}

// ---------------------------------------------------------------- launcher
extern "C" void kernel_launch(void* const* d_in, const int* in_sizes, int n_in,
                              void* d_out, int out_size, void* d_ws, size_t ws_size,
                              hipStream_t stream) {
    const float* x = (const float*)d_in[0];
    const int* tgt = (const int*)d_in[1];
    float* out = (float*)d_out;

    // ws: xq (1 MB) | sq (32 KB) | ce (32 KB) | ctl (32 KB) | pmax | pmin
    unsigned char* xq = (unsigned char*)d_ws;
    float* sq = (float*)(xq + (size_t)NB * 128);
    float* ce = sq + NB;
    unsigned* ctl = (unsigned*)(ce + NB);
    float* pmax = (float*)((unsigned char*)ctl + 32768);
    float* pmin = pmax + (size_t)16 * NB;

    k_prep<<<NB / 8, 256, 0, stream>>>(x, tgt, (unsigned*)xq, sq, ce, ctl);
    dim3 grid(NB / 64, NJS);
    k_trip<<<grid, 256, 0, stream>>>(xq, tgt, sq, ce, ctl, pmax, pmin, out);
}